// Round 1
// 1198.837 us; speedup vs baseline: 1.1287x; 1.1287x over previous
//
#include <hip/hip_runtime.h>
#include <hip/hip_fp16.h>

// Literal replication of the reference:
//   X = rfft(x, n=163839); H = rfft(h, n=163839); y = irfft(X*H)[:131072]
// N1=163839, N2=163838 -> Bluestein on L=2^18; four-step 512x512.
// R3: register+shuffle FFT-512, LDS only for layout conversion, row passes LDS-free.
// R4: all trig in TURNS via native v_sin/v_cos; COMBINE chirp pair collapsed.
// R5: ALL stored intermediates (V1, W, A, LDS tiles) in fp16 (__half2);
//     fp32 math in registers. Halves HBM traffic of every pass (3.3 GB -> 1.76 GB)
//     and halves the LDS tile (33280 -> 16640 B) so occupancy cap doubles.

#define L1FFT 262144
#define NCHAN 128
#define CN1 163839LL
#define CN2 163838LL
#define MBINS 81920
#define XLEN 131072
#define HLEN 32768
#define TWO_PI 6.28318530717958647692f
#define INV512T (1.0f/512.0f)
#define INVLT   (1.0f/262144.0f)
#define CHIRP12 ((float)(0.5 / (163839.0 * 163838.0)))   // turns per k^2

#define CM_BUILD   0
#define CM_REAL    1
#define CM_COMBINE 2
#define CM_EXTRACT 3
#define CM_FINAL   4
#define RM_BUILD   0
#define RM_CONV    1

// half2 tile row stride: 520 mod 32 == 8 -> worst LDS map is exactly 2-way (free)
#define TSTRIDE 520

__device__ __forceinline__ float2 cmulf(float2 a, float2 b) {
  return make_float2(a.x*b.x - a.y*b.y, a.x*b.y + a.y*b.x);
}
__device__ __forceinline__ float2 caddf(float2 a, float2 b){ return make_float2(a.x+b.x, a.y+b.y); }
__device__ __forceinline__ float2 csubf(float2 a, float2 b){ return make_float2(a.x-b.x, a.y-b.y); }

// e^{i*2pi*t}, |t| < 1 — native HW sin/cos take revolutions (v_sin_f32: sin(S0*2pi))
__device__ __forceinline__ float2 sc_turn(float t) {
  return make_float2(__builtin_amdgcn_cosf(t), __builtin_amdgcn_sinf(t));
}

// e^{sgn*i*pi*n^2/N1}: exact int64 mod by compile-time 2*N1, then turns
__device__ __forceinline__ float2 chirp1(float sgn, long long n) {
  long long m = (n*n) % (2*CN1);
  return sc_turn(sgn * (float)m * (1.0f/(float)(2*CN1)));
}
// e^{sgn*i*pi*n^2/N2}
__device__ __forceinline__ float2 chirp2(float sgn, long long n) {
  long long m = (n*n) % (2*CN2);
  return sc_turn(sgn * (float)m * (1.0f/(float)(2*CN2)));
}
// generic (runtime Q) — only used by the tiny BUILD dispatches
__device__ __forceinline__ float2 chirpv(float sgn, long long Q, long long n) {
  long long m = (n*n) % (2*Q);
  float ang = sgn * (0.5f*TWO_PI) * (float)m / (float)Q;
  float s, c; __sincosf(ang, &s, &c);
  return make_float2(c, s);
}

__device__ __forceinline__ int brev4(int x) {
  return ((x&1)<<3) | ((x&2)<<1) | ((x&4)>>1) | ((x&8)>>3);
}
__device__ __forceinline__ int brev5(int x) {
  return (int)(__brev((unsigned)x) >> 27);
}
__device__ __forceinline__ float2 shflx(float2 a, int m) {
  return make_float2(__shfl_xor(a.x, m, 64), __shfl_xor(a.y, m, 64));
}

#define C16_1 0.9238795325f
#define C16_2 0.7071067812f
#define C16_3 0.3826834324f
__device__ __forceinline__ float c16t(int j) {
  const float C[8] = {1.f, C16_1, C16_2, C16_3, 0.f, -C16_3, -C16_2, -C16_1};
  return C[j];
}
__device__ __forceinline__ float s16t(int j) {
  const float S[8] = {0.f, C16_3, C16_2, C16_1, 1.f, C16_1, C16_2, C16_3};
  return S[j];
}

// ---- in-lane 16-point DIF (forward, sign dsg): v[p] ends as F[brev4(p)] ----
__device__ __forceinline__ void lane16_fwd(float2 v[16], float dsg) {
  #pragma unroll
  for (int j = 0; j < 8; ++j) {
    float wr = c16t(j), wi = dsg * s16t(j);
    float2 a = v[j], b = v[j+8];
    v[j] = caddf(a, b);
    float2 tt = csubf(a, b);
    v[j+8] = make_float2(tt.x*wr - tt.y*wi, tt.x*wi + tt.y*wr);
  }
  #pragma unroll
  for (int h = 0; h < 2; ++h)
    #pragma unroll
    for (int j = 0; j < 4; ++j) {
      int i0 = h*8 + j;
      float wr = c16t(2*j), wi = dsg * s16t(2*j);
      float2 a = v[i0], b = v[i0+4];
      v[i0] = caddf(a, b);
      float2 tt = csubf(a, b);
      v[i0+4] = make_float2(tt.x*wr - tt.y*wi, tt.x*wi + tt.y*wr);
    }
  #pragma unroll
  for (int q = 0; q < 4; ++q)
    #pragma unroll
    for (int j = 0; j < 2; ++j) {
      int i0 = q*4 + j;
      float2 a = v[i0], b = v[i0+2];
      v[i0] = caddf(a, b);
      float2 tt = csubf(a, b);
      v[i0+2] = (j == 0) ? tt : make_float2(-dsg*tt.y, dsg*tt.x);
    }
  #pragma unroll
  for (int p = 0; p < 8; ++p) {
    float2 a = v[2*p], b = v[2*p+1];
    v[2*p] = caddf(a, b);
    v[2*p+1] = csubf(a, b);
  }
}

// ---- in-lane 16-point inverse-mirror ----
__device__ __forceinline__ void lane16_inv(float2 v[16], float dsg) {
  #pragma unroll
  for (int p = 0; p < 8; ++p) {
    float2 a = v[2*p], b = v[2*p+1];
    v[2*p] = caddf(a, b);
    v[2*p+1] = csubf(a, b);
  }
  #pragma unroll
  for (int q = 0; q < 4; ++q)
    #pragma unroll
    for (int j = 0; j < 2; ++j) {
      int i0 = q*4 + j;
      float2 a = v[i0], b = v[i0+2];
      float2 tb = (j == 0) ? b : make_float2(dsg*b.y, -dsg*b.x);
      v[i0] = caddf(a, tb);
      v[i0+2] = csubf(a, tb);
    }
  #pragma unroll
  for (int h = 0; h < 2; ++h)
    #pragma unroll
    for (int j = 0; j < 4; ++j) {
      int i0 = h*8 + j;
      float wr = c16t(2*j), wi = dsg * s16t(2*j);
      float2 a = v[i0], b = v[i0+4];
      float2 tb = make_float2(b.x*wr + b.y*wi, b.y*wr - b.x*wi);
      v[i0] = caddf(a, tb);
      v[i0+4] = csubf(a, tb);
    }
  #pragma unroll
  for (int j = 0; j < 8; ++j) {
    float wr = c16t(j), wi = dsg * s16t(j);
    float2 a = v[j], b = v[j+8];
    float2 tb = make_float2(b.x*wr + b.y*wi, b.y*wr - b.x*wi);
    v[j] = caddf(a, tb);
    v[j+8] = csubf(a, tb);
  }
}

// ---- cross-lane 32-point DIF over lanes (within 32-lane half-wave) ----
#define XFWD_STAGE(mask, w) {                                                  \
    bool hi = (l & (mask)) != 0;                                               \
    _Pragma("unroll")                                                          \
    for (int r = 0; r < 16; ++r) {                                             \
      float2 o = shflx(v[r], (mask));                                          \
      float2 d = hi ? csubf(o, v[r]) : caddf(v[r], o);                         \
      v[r] = hi ? cmulf(d, (w)) : d;                                           \
    } }
#define XFWD_PLAIN(mask) {                                                     \
    bool hi = (l & (mask)) != 0;                                               \
    _Pragma("unroll")                                                          \
    for (int r = 0; r < 16; ++r) {                                             \
      float2 o = shflx(v[r], (mask));                                          \
      v[r] = hi ? csubf(o, v[r]) : caddf(v[r], o);                             \
    } }
#define XINV_STAGE(mask, w) {                                                  \
    bool hi = (l & (mask)) != 0;                                               \
    _Pragma("unroll")                                                          \
    for (int r = 0; r < 16; ++r) {                                             \
      float2 b = hi ? make_float2(v[r].x*(w).x + v[r].y*(w).y,                 \
                                  v[r].y*(w).x - v[r].x*(w).y) : v[r];         \
      float2 o = shflx(b, (mask));                                             \
      v[r] = hi ? csubf(o, b) : caddf(b, o);                                   \
    } }
#define XINV_PLAIN(mask) {                                                     \
    bool hi = (l & (mask)) != 0;                                               \
    _Pragma("unroll")                                                          \
    for (int r = 0; r < 16; ++r) {                                             \
      float2 b = v[r];                                                         \
      float2 o = shflx(b, (mask));                                             \
      v[r] = hi ? csubf(o, b) : caddf(b, o);                                   \
    } }

// Full 512-pt forward: input lane l reg m = x[l+32m];
// output lane l reg r = X[brev4(r) + 16*brev5(l)].
__device__ __forceinline__ void fft512_fwd(float2 v[16], int l, float dsg) {
  lane16_fwd(v, dsg);
  #pragma unroll
  for (int r = 1; r < 16; ++r)                // W512^{l*brev4(r)} — exact turns
    v[r] = cmulf(v[r], sc_turn(dsg * INV512T * (float)(l * brev4(r))));
  float2 wA = sc_turn(dsg * (1.0f/32.0f) * (float)(l & 15));
  float2 wB = sc_turn(dsg * (1.0f/16.0f) * (float)(l & 7));
  float2 wC = sc_turn(dsg * (1.0f/8.0f)  * (float)(l & 3));
  float2 wD = (l&1) ? make_float2(0.f, dsg) : make_float2(1.f, 0.f);
  XFWD_STAGE(16, wA); XFWD_STAGE(8, wB); XFWD_STAGE(4, wC);
  XFWD_STAGE(2, wD);  XFWD_PLAIN(1);
}

// Unnormalized inverse (x512) of fft512_fwd(dsg)
__device__ __forceinline__ void fft512_inv(float2 v[16], int l, float dsg) {
  float2 wA = sc_turn(dsg * (1.0f/32.0f) * (float)(l & 15));
  float2 wB = sc_turn(dsg * (1.0f/16.0f) * (float)(l & 7));
  float2 wC = sc_turn(dsg * (1.0f/8.0f)  * (float)(l & 3));
  float2 wD = (l&1) ? make_float2(0.f, dsg) : make_float2(1.f, 0.f);
  XINV_PLAIN(1); XINV_STAGE(2, wD); XINV_STAGE(4, wC);
  XINV_STAGE(8, wB); XINV_STAGE(16, wA);
  #pragma unroll
  for (int r = 1; r < 16; ++r)
    v[r] = cmulf(v[r], sc_turn(-dsg * INV512T * (float)(l * brev4(r))));
  lane16_inv(v, dsg);
}

// ---------------- column pass ----------------
__global__ __launch_bounds__(256) void pass_col_k(
    int mode,
    const float* __restrict__ realSrc, int realLen,
    const __half2* cplxSrc,
    const __half2* __restrict__ hcIn,
    __half2* dstFull,
    __half2* __restrict__ specOut,
    float* __restrict__ realOut,
    long long Q, float csgn, int lo, int hi)
{
  // fp16 tile: 8*520*4 = 16640 B (CM_FINAL aliases it as float[8*513] = 16416 B)
  __shared__ __align__(16) unsigned char ldsraw[8 * TSTRIDE * 4];
  __half2* tile = (__half2*)ldsraw;
  const int t   = threadIdx.x;
  const int c0  = blockIdx.x * 8;
  const int ch  = blockIdx.y;
  const int l   = t & 31;
  const int ccf = t >> 5;
  const int c   = c0 + ccf;
  float2 v[16];

  if (mode == CM_BUILD) {
    #pragma unroll
    for (int m = 0; m < 16; ++m) {
      int n = ((l + 32*m) << 9) + c;
      int np = (n <= hi) ? n : n - L1FFT;
      v[m] = (np >= lo) ? chirpv(csgn, Q, (long long)np) : make_float2(0.f, 0.f);
    }
  } else if (mode == CM_REAL) {
    #pragma unroll
    for (int i = 0; i < 16; ++i) {
      int qq = t + 256*i;
      int cc = qq & 7, r = qq >> 3;
      int n = (r << 9) + c0 + cc;
      float2 val = make_float2(0.f, 0.f);
      if (n < realLen) {
        float xv = realSrc[(size_t)ch * realLen + n];
        float2 cw = chirp1(-1.f, (long long)n);        // pre-chirp
        val = make_float2(xv*cw.x, xv*cw.y);
      }
      tile[cc*TSTRIDE + r] = __float22half2_rn(val);
    }
    __syncthreads();
    #pragma unroll
    for (int m = 0; m < 16; ++m) v[m] = __half22float2(tile[ccf*TSTRIDE + l + 32*m]);
    __syncthreads();
  } else {
    #pragma unroll
    for (int i = 0; i < 16; ++i) {
      int qq = t + 256*i;
      int cc = qq & 7, z = qq >> 3;
      int la = z & 31, ra = z >> 5;
      int j = brev4(ra) + 16*brev5(la);
      tile[cc*TSTRIDE + la + 32*ra] = cplxSrc[(size_t)ch*L1FFT + (j << 9) + c0 + cc];
    }
    __syncthreads();
    #pragma unroll
    for (int m = 0; m < 16; ++m) v[m] = __half22float2(tile[ccf*TSTRIDE + l + 32*m]);
    __syncthreads();
  }

  if (mode == CM_COMBINE) {
    fft512_inv(v, l, -1.f);         // completes X's Bluestein conv
    #pragma unroll
    for (int m = 0; m < 16; ++m) {
      if (m <= 4) {                 // n < 160 <=> k < MBINS
        int n = l + 32*m;
        long long k = ((long long)n << 9) + c;
        // postchirp1*prechirp2 = e^{+i pi k^2/(N1*N2)} (N1-N2=1); no mod needed
        float fk = (float)k;
        float2 w = sc_turn(fk * fk * CHIRP12);
        float2 H = __half22float2(hcIn[(size_t)ch*MBINS + c*160 + n]);
        float2 Y = cmulf(v[m], H);
        float eps = (k == 0 || k == MBINS-1) ? 1.f : 2.f;
        float sc = eps / (float)CN2;
        v[m] = cmulf(make_float2(Y.x*sc, Y.y*sc), w);
      } else v[m] = make_float2(0.f, 0.f);
    }
  }

  if (mode <= CM_COMBINE) {         // BUILD / REAL / COMBINE: fwd FFT + store
    fft512_fwd(v, l, -1.f);
    #pragma unroll
    for (int r = 0; r < 16; ++r) {  // four-step twiddle (exact turns) + slot write
      int k1 = brev4(r), k2 = brev5(l);
      int kf = k1 + 16*k2;
      float2 w = sc_turn(-INVLT * (float)(c * kf));
      tile[ccf*TSTRIDE + k2 + 32*k1] = __float22half2_rn(cmulf(v[r], w));
    }
    __syncthreads();
    {
      int cc = t & 7, u = t >> 3;
      #pragma unroll
      for (int i = 0; i < 16; ++i)
        dstFull[(size_t)ch*L1FFT + ((i + 16*u) << 9) + c0 + cc] =
            tile[cc*TSTRIDE + u + 32*i];
    }
  } else if (mode == CM_EXTRACT) {
    fft512_inv(v, l, -1.f);
    #pragma unroll
    for (int m = 0; m <= 4; ++m) {
      int n = l + 32*m;
      long long k = ((long long)n << 9) + c;
      float2 cw = chirp1(-1.f, k);
      specOut[(size_t)ch*MBINS + c*160 + n] = __float22half2_rn(cmulf(v[m], cw));
    }
  } else {                          // CM_FINAL
    fft512_inv(v, l, -1.f);
    float* tf = (float*)ldsraw;
    #pragma unroll
    for (int m = 0; m < 8; ++m) {
      int n = l + 32*m;
      long long nb = ((long long)n << 9) + c;
      float2 cw = chirp2(+1.f, nb);
      tf[ccf*513 + n] = v[m].x*cw.x - v[m].y*cw.y;
    }
    __syncthreads();
    {
      int cc = t & 7, u = t >> 3;
      #pragma unroll
      for (int i = 0; i < 8; ++i) {
        int n = u + 32*i;
        realOut[(size_t)ch*XLEN + (n << 9) + c0 + cc] = tf[cc*513 + n];
      }
    }
  }
}

// ---------------- row pass (LDS-free) ----------------
__global__ __launch_bounds__(256) void pass_row_k(
    int mode, __half2* a, const __half2* __restrict__ g)
{
  const int t = threadIdx.x;
  const int l = t & 31;
  const int row = blockIdx.x * 8 + (t >> 5);
  const int ch = blockIdx.y;
  __half2* A = a + (size_t)ch * L1FFT + (size_t)row * 512;
  float2 v[16];
  #pragma unroll
  for (int m = 0; m < 16; ++m) v[m] = __half22float2(A[l + 32*m]);

  if (mode == RM_CONV) {
    const __half2* G = g + (size_t)row * 512;
    float2 gv[16];
    #pragma unroll
    for (int m = 0; m < 16; ++m) gv[m] = __half22float2(G[l + 32*m]);
    fft512_fwd(v, l, -1.f);
    #pragma unroll
    for (int r = 0; r < 16; ++r) v[r] = cmulf(v[r], gv[r]);
    fft512_inv(v, l, -1.f);
    #pragma unroll
    for (int m = 0; m < 16; ++m) {
      int cidx = l + 32*m;
      float2 w = sc_turn(INVLT * (float)(cidx * row));   // conj four-step twiddle
      float2 r_ = cmulf(v[m], w);
      A[cidx] = __float22half2_rn(
          make_float2(r_.x * (1.f/(float)L1FFT), r_.y * (1.f/(float)L1FFT)));
    }
  } else {
    fft512_fwd(v, l, -1.f);
    #pragma unroll
    for (int r = 0; r < 16; ++r) A[l + 32*r] = __float22half2_rn(v[r]);  // FFT-state order
  }
}

__global__ void diag_ws_too_small(float* out) { out[0] = 123456.0f; }

extern "C" void kernel_launch(void* const* d_in, const int* in_sizes, int n_in,
                              void* d_out, int out_size, void* d_ws, size_t ws_size,
                              hipStream_t stream) {
  const float* x = (const float*)d_in[0];   // (32,4,131072) f32
  const float* h = (const float*)d_in[1];   // (32,4,32768)  f32
  float* out = (float*)d_out;

  const size_t fixedB   = 2ull * L1FFT * sizeof(__half2);
  const size_t perChanB = (size_t)L1FFT * sizeof(__half2) + (size_t)MBINS * sizeof(__half2);
  if (ws_size < fixedB + perChanB) {
    diag_ws_too_small<<<1, 1, 0, stream>>>(out);
    return;
  }
  int chunk = (int)((ws_size - fixedB) / perChanB);
  if (chunk > NCHAN) chunk = NCHAN;

  __half2* V1 = (__half2*)d_ws;
  __half2* W  = V1 + L1FFT;
  __half2* A  = W + L1FFT;
  __half2* Hc = A + (size_t)chunk * L1FFT;

  dim3 blk(256);
  dim3 g1(64, 1);

  // chirp-kernel spectra (channel-independent)
  pass_col_k<<<g1, blk, 0, stream>>>(CM_BUILD, nullptr, 0, nullptr, nullptr,
                                     V1, nullptr, nullptr, CN1, +1.f, -(XLEN-1), MBINS-1);
  pass_row_k<<<g1, blk, 0, stream>>>(RM_BUILD, V1, nullptr);
  pass_col_k<<<g1, blk, 0, stream>>>(CM_BUILD, nullptr, 0, nullptr, nullptr,
                                     W, nullptr, nullptr, CN2, -1.f, -(MBINS-1), XLEN-1);
  pass_row_k<<<g1, blk, 0, stream>>>(RM_BUILD, W, nullptr);

  for (int ch0 = 0; ch0 < NCHAN; ch0 += chunk) {
    int nc = NCHAN - ch0; if (nc > chunk) nc = chunk;
    dim3 gC(64, nc);
    const float* hq = h   + (size_t)ch0 * HLEN;
    const float* xq = x   + (size_t)ch0 * XLEN;
    float*       oq = out + (size_t)ch0 * XLEN;

    // H[k] -> Hc ([c][n] layout, half2, postchirp applied)
    pass_col_k<<<gC, blk, 0, stream>>>(CM_REAL, hq, HLEN, nullptr, nullptr,
                                       A, nullptr, nullptr, CN1, 0.f, 0, 0);
    pass_row_k<<<gC, blk, 0, stream>>>(RM_CONV, A, V1);
    pass_col_k<<<gC, blk, 0, stream>>>(CM_EXTRACT, nullptr, 0, A, nullptr,
                                       nullptr, Hc, nullptr, CN1, 0.f, 0, 0);

    // X path + combine + inverse-chirp transform
    pass_col_k<<<gC, blk, 0, stream>>>(CM_REAL, xq, XLEN, nullptr, nullptr,
                                       A, nullptr, nullptr, CN1, 0.f, 0, 0);
    pass_row_k<<<gC, blk, 0, stream>>>(RM_CONV, A, V1);
    pass_col_k<<<gC, blk, 0, stream>>>(CM_COMBINE, nullptr, 0, A, Hc,
                                       A, nullptr, nullptr, CN2, 0.f, 0, 0);
    pass_row_k<<<gC, blk, 0, stream>>>(RM_CONV, A, W);
    pass_col_k<<<gC, blk, 0, stream>>>(CM_FINAL, nullptr, 0, A, nullptr,
                                       nullptr, nullptr, oq, CN2, 0.f, 0, 0);
  }
}